// Round 6
// baseline (77.167 us; speedup 1.0000x reference)
//
#include <hip/hip_runtime.h>

#define S_SCALE 64.0f
#define M_MARGIN 0.35f

typedef float f32x4 __attribute__((ext_vector_type(4)));

// ---------------------------------------------------------------------------
// Single fused kernel.
//
// diff part: out[b,j] = S * (logits[b, j + (j>=l)] - (t - M))
//   Out element (b,j) is 16B-aligned iff j === b (mod 4) [C-1=99999===3 mod 4].
//   Input row base b*C is 16B-aligned (C=100000 div by 4), so with S = b&3
//   the 12-float window rin[j-S .. j-S+11] is 16B-aligned and covers all
//   gather sources c = j+i+(j+i>=l), i in 0..7 (max index S+8 <= 11).
//   Each thread: 3 aligned dwordx4 loads -> 8 selects -> 2 NT dwordx4 stores.
//   S is uniform per row -> templated switch keeps register indexing static.
//   NT stores keep the 205MB output stream from evicting logits out of L3.
//   Last tile: cap av at a1-16 (NOT a1-12!) so av-a0 stays a multiple of 8 —
//   the 8-wide chunk grid must land exactly on av or elements are skipped
//   (that was the R5 bug: av-a0 === 4 mod 8 left 4 unwritten elems per row).
//
// stats part (fused, blockIdx.x==0 & tid==0 per row):
//   sin(acos(x)) = sqrt(1-x^2) exactly; sin(tm-t) = stm*t - ft*st.
// ---------------------------------------------------------------------------
constexpr int C_CONST   = 100000;
constexpr int CM1_CONST = 99999;
constexpr int TILE      = 4096;   // output elements per block

template <int S>
__device__ __forceinline__ void diff_row_body(const float* __restrict__ rin,
                                              float* __restrict__ rout,
                                              int l, float nsft,
                                              int a0, int av, int tid) {
    for (int j = a0 + tid * 8; j + 8 <= av; j += 256 * 8) {
        const f32x4 w0 = *reinterpret_cast<const f32x4*>(rin + (j - S));
        const f32x4 w1 = *reinterpret_cast<const f32x4*>(rin + (j - S) + 4);
        const f32x4 w2 = *reinterpret_cast<const f32x4*>(rin + (j - S) + 8);
        const float w[12] = {w0.x, w0.y, w0.z, w0.w,
                             w1.x, w1.y, w1.z, w1.w,
                             w2.x, w2.y, w2.z, w2.w};
        f32x4 v0, v1;
        v0.x = fmaf(S_SCALE, ((j + 0 >= l) ? w[S + 1] : w[S + 0]), nsft);
        v0.y = fmaf(S_SCALE, ((j + 1 >= l) ? w[S + 2] : w[S + 1]), nsft);
        v0.z = fmaf(S_SCALE, ((j + 2 >= l) ? w[S + 3] : w[S + 2]), nsft);
        v0.w = fmaf(S_SCALE, ((j + 3 >= l) ? w[S + 4] : w[S + 3]), nsft);
        v1.x = fmaf(S_SCALE, ((j + 4 >= l) ? w[S + 5] : w[S + 4]), nsft);
        v1.y = fmaf(S_SCALE, ((j + 5 >= l) ? w[S + 6] : w[S + 5]), nsft);
        v1.z = fmaf(S_SCALE, ((j + 6 >= l) ? w[S + 7] : w[S + 6]), nsft);
        v1.w = fmaf(S_SCALE, ((j + 7 >= l) ? w[S + 8] : w[S + 7]), nsft);
        __builtin_nontemporal_store(v0, reinterpret_cast<f32x4*>(rout + j));
        __builtin_nontemporal_store(v1, reinterpret_cast<f32x4*>(rout + j + 4));
    }
}

__global__ __launch_bounds__(256) void cosface_fused_kernel(
        const float* __restrict__ logits,
        const int* __restrict__ labels,
        float* __restrict__ out, int B) {
    const int b = blockIdx.y;                       // uniform
    const int l = labels[b];                        // s_load
    const float t  = logits[(size_t)b * C_CONST + l];
    const float ft = t - M_MARGIN;
    const float nsft = -S_SCALE * ft;
    const float* __restrict__ rin  = logits + (size_t)b * C_CONST;
    float* __restrict__ rout       = out    + (size_t)b * CM1_CONST;

    const int tid = threadIdx.x;

    // fused per-row stats (one thread of one block per row)
    if (blockIdx.x == 0 && tid == 0) {
        float st  = sqrtf(fmaxf(1.0f - t * t, 0.0f));
        float stm = sqrtf(fmaxf(1.0f - ft * ft, 0.0f));
        float sm  = stm * t - ft * st;
        size_t base = (size_t)B * (size_t)CM1_CONST;
        out[base + b]           = st;   // sin_theta
        out[base + B + b]       = stm;  // sin_theta_plus_m
        out[base + 2 * B + b]   = sm;   // sin_m
    }

    const int e0 = blockIdx.x * TILE;
    const int e1 = min(e0 + TILE, CM1_CONST);
    // first 16B-aligned output index in [e0, e1]
    int a0 = e0 + ((b - e0) & 3);
    if (a0 > e1) a0 = e1;
    int a1 = a0 + ((e1 - a0) & ~7);
    // keep the 12-float load window inside the logits row near the row end;
    // subtract a MULTIPLE OF 8 so the 8-wide chunk grid still ends at av
    const int av = (e1 == CM1_CONST) ? max(a0, a1 - 16) : a1;

    switch (b & 3) {
        case 0: diff_row_body<0>(rin, rout, l, nsft, a0, av, tid); break;
        case 1: diff_row_body<1>(rin, rout, l, nsft, a0, av, tid); break;
        case 2: diff_row_body<2>(rin, rout, l, nsft, a0, av, tid); break;
        default: diff_row_body<3>(rin, rout, l, nsft, a0, av, tid); break;
    }

    // scalar edges: [e0, a0) head (<=3), [av, e1) tail (<=23)
    const int n1 = a0 - e0;
    if (tid < n1) {
        int j = e0 + tid;
        int c = j + (j >= l);
        rout[j] = fmaf(S_SCALE, rin[c], nsft);
    }
    const int n2 = e1 - av;
    if (tid < n2) {
        int j = av + tid;
        int c = j + (j >= l);
        rout[j] = fmaf(S_SCALE, rin[c], nsft);
    }
}

extern "C" void kernel_launch(void* const* d_in, const int* in_sizes, int n_in,
                              void* d_out, int out_size, void* d_ws, size_t ws_size,
                              hipStream_t stream) {
    const float* logits = (const float*)d_in[0];
    const int*   labels = (const int*)d_in[1];
    float*       out    = (float*)d_out;

    const int B = in_sizes[1];          // 512

    dim3 block(256);
    dim3 grid((CM1_CONST + TILE - 1) / TILE, B);   // (25, 512)
    cosface_fused_kernel<<<grid, block, 0, stream>>>(logits, labels, out, B);
}

// Round 7
// 67.299 us; speedup vs baseline: 1.1466x; 1.1466x over previous
//
#include <hip/hip_runtime.h>

#define S_SCALE 64.0f
#define M_MARGIN 0.35f

typedef float f32x4 __attribute__((ext_vector_type(4)));

// ---------------------------------------------------------------------------
// Single fused kernel.
//
// diff part: out[b,j] = S * (logits[b, j + (j>=l)] - (t - M))
//   Out element (b,j) is 16B-aligned iff j === b (mod 4) [C-1=99999===3 mod 4].
//   Input row base b*C is 16B-aligned (C=100000 div by 4), so with S = b&3
//   the 8-float window rin[j-S .. j-S+7] is 16B-aligned and covers all gather
//   sources c = j+i+(j+i>=l), i in 0..3 (max index S+4 <= 7).
//   Each thread: 2 aligned dwordx4 loads -> 4 selects -> 1 NT dwordx4 store.
//   CONTIGUITY RULE (R6 lesson): j = a0 + tid*4 keeps every load/store
//   instruction lane-contiguous (16B stride across lanes). The 8-outputs/
//   thread variant (tid*8) made each instruction 32B-strided -> NT partial-
//   line writes -> WRITE_SIZE +11% and a 5us regression.
//   NT stores keep the 205MB output stream from evicting logits out of L3.
//
// stats part (fused, blockIdx.x==0 & tid==0 per row):
//   sin(acos(x)) = sqrt(1-x^2) exactly; sin(tm-t) = stm*t - ft*st.
// ---------------------------------------------------------------------------
constexpr int C_CONST   = 100000;
constexpr int CM1_CONST = 99999;
constexpr int TILE      = 4096;   // output elements per block

template <int S>
__device__ __forceinline__ void diff_row_body(const float* __restrict__ rin,
                                              float* __restrict__ rout,
                                              int l, float nsft,
                                              int a0, int av, int tid) {
    for (int j = a0 + tid * 4; j + 4 <= av; j += 256 * 4) {
        const f32x4 w0 = *reinterpret_cast<const f32x4*>(rin + (j - S));
        const f32x4 w1 = *reinterpret_cast<const f32x4*>(rin + (j - S) + 4);
        const float w[8] = {w0.x, w0.y, w0.z, w0.w, w1.x, w1.y, w1.z, w1.w};
        f32x4 v;
        v.x = fmaf(S_SCALE, ((j + 0 >= l) ? w[S + 1] : w[S + 0]), nsft);
        v.y = fmaf(S_SCALE, ((j + 1 >= l) ? w[S + 2] : w[S + 1]), nsft);
        v.z = fmaf(S_SCALE, ((j + 2 >= l) ? w[S + 3] : w[S + 2]), nsft);
        v.w = fmaf(S_SCALE, ((j + 3 >= l) ? w[S + 4] : w[S + 3]), nsft);
        __builtin_nontemporal_store(v, reinterpret_cast<f32x4*>(rout + j));
    }
}

__global__ __launch_bounds__(256) void cosface_fused_kernel(
        const float* __restrict__ logits,
        const int* __restrict__ labels,
        float* __restrict__ out, int B) {
    const int b = blockIdx.y;                       // uniform
    const int l = labels[b];                        // s_load
    const float t  = logits[(size_t)b * C_CONST + l];
    const float ft = t - M_MARGIN;
    const float nsft = -S_SCALE * ft;
    const float* __restrict__ rin  = logits + (size_t)b * C_CONST;
    float* __restrict__ rout       = out    + (size_t)b * CM1_CONST;

    const int tid = threadIdx.x;

    // fused per-row stats (one thread of one block per row)
    if (blockIdx.x == 0 && tid == 0) {
        float st  = sqrtf(fmaxf(1.0f - t * t, 0.0f));
        float stm = sqrtf(fmaxf(1.0f - ft * ft, 0.0f));
        float sm  = stm * t - ft * st;
        size_t base = (size_t)B * (size_t)CM1_CONST;
        out[base + b]           = st;   // sin_theta
        out[base + B + b]       = stm;  // sin_theta_plus_m
        out[base + 2 * B + b]   = sm;   // sin_m
    }

    const int e0 = blockIdx.x * TILE;
    const int e1 = min(e0 + TILE, CM1_CONST);
    // first 16B-aligned output index in [e0, e1]
    int a0 = e0 + ((b - e0) & 3);
    if (a0 > e1) a0 = e1;
    int a1 = a0 + ((e1 - a0) & ~3);
    // keep the 8-float load window inside the logits row near the row end;
    // subtract a multiple of 4 so the 4-wide chunk grid still ends at av
    const int av = (e1 == CM1_CONST) ? max(a0, a1 - 8) : a1;

    switch (b & 3) {
        case 0: diff_row_body<0>(rin, rout, l, nsft, a0, av, tid); break;
        case 1: diff_row_body<1>(rin, rout, l, nsft, a0, av, tid); break;
        case 2: diff_row_body<2>(rin, rout, l, nsft, a0, av, tid); break;
        default: diff_row_body<3>(rin, rout, l, nsft, a0, av, tid); break;
    }

    // scalar edges: [e0, a0) head (<=3), [av, e1) tail (<=11)
    const int n1 = a0 - e0;
    if (tid < n1) {
        int j = e0 + tid;
        int c = j + (j >= l);
        rout[j] = fmaf(S_SCALE, rin[c], nsft);
    }
    const int n2 = e1 - av;
    if (tid < n2) {
        int j = av + tid;
        int c = j + (j >= l);
        rout[j] = fmaf(S_SCALE, rin[c], nsft);
    }
}

extern "C" void kernel_launch(void* const* d_in, const int* in_sizes, int n_in,
                              void* d_out, int out_size, void* d_ws, size_t ws_size,
                              hipStream_t stream) {
    const float* logits = (const float*)d_in[0];
    const int*   labels = (const int*)d_in[1];
    float*       out    = (float*)d_out;

    const int B = in_sizes[1];          // 512

    dim3 block(256);
    dim3 grid((CM1_CONST + TILE - 1) / TILE, B);   // (25, 512)
    cosface_fused_kernel<<<grid, block, 0, stream>>>(logits, labels, out, B);
}

// Round 8
// 66.934 us; speedup vs baseline: 1.1529x; 1.0054x over previous
//
#include <hip/hip_runtime.h>

#define S_SCALE 64.0f
#define M_MARGIN 0.35f

typedef float f32x4 __attribute__((ext_vector_type(4)));

// ---------------------------------------------------------------------------
// Single fused kernel.
//
// diff part: out[b,j] = S * (logits[b, j + (j>=l)] - (t - M))
//   Out element (b,j) is 16B-aligned iff j === b (mod 4) [C-1=99999===3 mod 4].
//   Input row base b*C is 16B-aligned (C=100000 div by 4), so with S = b&3
//   the 8-float window rin[j-S .. j-S+7] is 16B-aligned and covers all gather
//   sources c = j+i+(j+i>=l), i in 0..3 (max index S+4 <= 7).
//   Each thread: 2 aligned dwordx4 loads -> 4 selects -> 1 streaming store.
//   CONTIGUITY RULE (R6 lesson): j = a0 + tid*4 keeps every load/store
//   instruction lane-contiguous (16B stride across lanes); tid*8 regressed
//   (strided partial-line NT writes, WRITE_SIZE +11%).
//   R8 experiment: store via inline asm "sc0 sc1 nt" — full cache-bypass bit
//   set — trying to stop the 205MB write stream from allocating in L2/MALL
//   so the 204.8MB logits array stays L3-resident across graph replays
//   (plain `nt` builtin left FETCH_SIZE at ~101MB/replay).
//
// stats part (fused, blockIdx.x==0 & tid==0 per row):
//   sin(acos(x)) = sqrt(1-x^2) exactly; sin(tm-t) = stm*t - ft*st.
// ---------------------------------------------------------------------------
constexpr int C_CONST   = 100000;
constexpr int CM1_CONST = 99999;
constexpr int TILE      = 4096;   // output elements per block

__device__ __forceinline__ void stream_store(float* p, f32x4 v) {
    asm volatile("global_store_dwordx4 %0, %1, off sc0 sc1 nt"
                 :: "v"(p), "v"(v) : "memory");
}

template <int S>
__device__ __forceinline__ void diff_row_body(const float* __restrict__ rin,
                                              float* __restrict__ rout,
                                              int l, float nsft,
                                              int a0, int av, int tid) {
    for (int j = a0 + tid * 4; j + 4 <= av; j += 256 * 4) {
        const f32x4 w0 = *reinterpret_cast<const f32x4*>(rin + (j - S));
        const f32x4 w1 = *reinterpret_cast<const f32x4*>(rin + (j - S) + 4);
        const float w[8] = {w0.x, w0.y, w0.z, w0.w, w1.x, w1.y, w1.z, w1.w};
        f32x4 v;
        v.x = fmaf(S_SCALE, ((j + 0 >= l) ? w[S + 1] : w[S + 0]), nsft);
        v.y = fmaf(S_SCALE, ((j + 1 >= l) ? w[S + 2] : w[S + 1]), nsft);
        v.z = fmaf(S_SCALE, ((j + 2 >= l) ? w[S + 3] : w[S + 2]), nsft);
        v.w = fmaf(S_SCALE, ((j + 3 >= l) ? w[S + 4] : w[S + 3]), nsft);
        stream_store(rout + j, v);
    }
}

__global__ __launch_bounds__(256) void cosface_fused_kernel(
        const float* __restrict__ logits,
        const int* __restrict__ labels,
        float* __restrict__ out, int B) {
    const int b = blockIdx.y;                       // uniform
    const int l = labels[b];                        // s_load
    const float t  = logits[(size_t)b * C_CONST + l];
    const float ft = t - M_MARGIN;
    const float nsft = -S_SCALE * ft;
    const float* __restrict__ rin  = logits + (size_t)b * C_CONST;
    float* __restrict__ rout       = out    + (size_t)b * CM1_CONST;

    const int tid = threadIdx.x;

    // fused per-row stats (one thread of one block per row)
    if (blockIdx.x == 0 && tid == 0) {
        float st  = sqrtf(fmaxf(1.0f - t * t, 0.0f));
        float stm = sqrtf(fmaxf(1.0f - ft * ft, 0.0f));
        float sm  = stm * t - ft * st;
        size_t base = (size_t)B * (size_t)CM1_CONST;
        out[base + b]           = st;   // sin_theta
        out[base + B + b]       = stm;  // sin_theta_plus_m
        out[base + 2 * B + b]   = sm;   // sin_m
    }

    const int e0 = blockIdx.x * TILE;
    const int e1 = min(e0 + TILE, CM1_CONST);
    // first 16B-aligned output index in [e0, e1]
    int a0 = e0 + ((b - e0) & 3);
    if (a0 > e1) a0 = e1;
    int a1 = a0 + ((e1 - a0) & ~3);
    // keep the 8-float load window inside the logits row near the row end;
    // subtract a multiple of 4 so the 4-wide chunk grid still ends at av
    const int av = (e1 == CM1_CONST) ? max(a0, a1 - 8) : a1;

    switch (b & 3) {
        case 0: diff_row_body<0>(rin, rout, l, nsft, a0, av, tid); break;
        case 1: diff_row_body<1>(rin, rout, l, nsft, a0, av, tid); break;
        case 2: diff_row_body<2>(rin, rout, l, nsft, a0, av, tid); break;
        default: diff_row_body<3>(rin, rout, l, nsft, a0, av, tid); break;
    }

    // scalar edges: [e0, a0) head (<=3), [av, e1) tail (<=11)
    const int n1 = a0 - e0;
    if (tid < n1) {
        int j = e0 + tid;
        int c = j + (j >= l);
        rout[j] = fmaf(S_SCALE, rin[c], nsft);
    }
    const int n2 = e1 - av;
    if (tid < n2) {
        int j = av + tid;
        int c = j + (j >= l);
        rout[j] = fmaf(S_SCALE, rin[c], nsft);
    }
}

extern "C" void kernel_launch(void* const* d_in, const int* in_sizes, int n_in,
                              void* d_out, int out_size, void* d_ws, size_t ws_size,
                              hipStream_t stream) {
    const float* logits = (const float*)d_in[0];
    const int*   labels = (const int*)d_in[1];
    float*       out    = (float*)d_out;

    const int B = in_sizes[1];          // 512

    dim3 block(256);
    dim3 grid((CM1_CONST + TILE - 1) / TILE, B);   // (25, 512)
    cosface_fused_kernel<<<grid, block, 0, stream>>>(logits, labels, out, B);
}